// Round 1
// baseline (112.256 us; speedup 1.0000x reference)
//
#include <hip/hip_runtime.h>

#define HIDDEN 32
#define NOUT 9

// tanh(x) = 1 - 2/(exp(2x)+1)  — monotone, saturates correctly at +-inf
__device__ __forceinline__ float fast_tanh(float v) {
    float e = __expf(2.0f * v);
    return 1.0f - __fdividef(2.0f, e + 1.0f);
}

// One group (3 consecutive edges) per 8-lane subwave.
// Lane l of a subwave owns float4 chunk l of each gathered 32-float row:
//   lanes 0..7 cover channels 0..31 (src half); the dst half uses W[j][32+4l..].
__global__ __launch_bounds__(256) void sheaf_kernel(
    const float* __restrict__ x,          // [N_ROWS, 32]
    const int*   __restrict__ edge_index, // [2, E] int32
    const float* __restrict__ W,          // [9, 64]
    float*       __restrict__ out,        // [G, 9]
    int G, int E)
{
    __shared__ float Wlds[NOUT * 64];   // 576 floats = 2.25 KB
    for (int i = threadIdx.x; i < NOUT * 64; i += 256) Wlds[i] = W[i];
    __syncthreads();

    const int l    = threadIdx.x & 7;                       // lane within subwave
    const int sub0 = (blockIdx.x * 256 + threadIdx.x) >> 3; // subwave id
    const int nsub = (gridDim.x * 256) >> 3;

    const float4* Wv = reinterpret_cast<const float4*>(Wlds);
    const float4* Xv = reinterpret_cast<const float4*>(x);

    for (int g = sub0; g < G; g += nsub) {
        const int* sp = edge_index + 3 * g;
        const int* dp = edge_index + E + 3 * g;

        float4 xs = make_float4(0.f, 0.f, 0.f, 0.f);
        float4 xd = make_float4(0.f, 0.f, 0.f, 0.f);
        #pragma unroll
        for (int k = 0; k < 3; ++k) {
            int si = sp[k];
            float4 v = Xv[si * 8 + l];          // coalesced 128B across 8 lanes
            xs.x += v.x; xs.y += v.y; xs.z += v.z; xs.w += v.w;
        }
        #pragma unroll
        for (int k = 0; k < 3; ++k) {
            int di = dp[k];
            float4 v = Xv[di * 8 + l];
            xd.x += v.x; xd.y += v.y; xd.z += v.z; xd.w += v.w;
        }

        float myv = 0.f, extra = 0.f;
        #pragma unroll
        for (int j = 0; j < NOUT; ++j) {
            float4 ws = Wv[j * 16 + l];         // W[j][4l..4l+3]       (src half)
            float4 wd = Wv[j * 16 + 8 + l];     // W[j][32+4l..32+4l+3] (dst half)
            float s = xs.x * ws.x + xs.y * ws.y + xs.z * ws.z + xs.w * ws.w
                    + xd.x * wd.x + xd.y * wd.y + xd.z * wd.z + xd.w * wd.w;
            s += __shfl_xor(s, 1);
            s += __shfl_xor(s, 2);
            s += __shfl_xor(s, 4);
            if (j < 8) {
                if (l == j) myv = s;            // lane j keeps output j (no array)
            } else {
                extra = s;                      // output 8, written by lane 0
            }
        }
        out[g * 9 + l] = fast_tanh(myv);
        if (l == 0) out[g * 9 + 8] = fast_tanh(extra);
    }
}

extern "C" void kernel_launch(void* const* d_in, const int* in_sizes, int n_in,
                              void* d_out, int out_size, void* d_ws, size_t ws_size,
                              hipStream_t stream) {
    const float* x  = (const float*)d_in[0];
    const int*   ei = (const int*)d_in[1];
    const float* W  = (const float*)d_in[2];
    float*       out = (float*)d_out;

    const int E = in_sizes[1] / 2;   // 3,000,000
    const int G = E / 3;             // 1,000,000

    const int blocks = 4096;         // grid-stride; ~7.6 groups per subwave
    hipLaunchKernelGGL(sheaf_kernel, dim3(blocks), dim3(256), 0, stream,
                       x, ei, W, out, G, E);
}

// Round 2
// 109.528 us; speedup vs baseline: 1.0249x; 1.0249x over previous
//
#include <hip/hip_runtime.h>

#define HIDDEN 32
#define NOUT 9

__device__ __forceinline__ float fast_tanh(float v) {
    float e = __expf(2.0f * v);
    return 1.0f - __fdividef(2.0f, e + 1.0f);
}

__device__ __forceinline__ float dot4(float4 a, float4 b) {
    return a.x * b.x + a.y * b.y + a.z * b.z + a.w * b.w;
}

// One 8-lane subwave handles TWO groups (6 edges). All 12 row-gathers are
// issued back-to-back before any use -> 2x memory-level parallelism vs the
// grid-stride 1-group version. No loop: exact launch.
__global__ __launch_bounds__(256) void sheaf_kernel(
    const float* __restrict__ x,          // [N_ROWS, 32]
    const int*   __restrict__ edge_index, // [2, E] int32
    const float* __restrict__ W,          // [9, 64]
    float*       __restrict__ out,        // [G, 9]
    int G, int E)
{
    __shared__ float Wlds[NOUT * 64];
    for (int i = threadIdx.x; i < NOUT * 64; i += 256) Wlds[i] = W[i];
    __syncthreads();

    const int l = threadIdx.x & 7;
    const int s = (blockIdx.x * 256 + threadIdx.x) >> 3;  // subwave id
    const int g0 = 2 * s;
    const int g1 = 2 * s + 1;
    if (g0 >= G) return;
    const bool has1 = (g1 < G);

    const float4* Xv = reinterpret_cast<const float4*>(x);
    const float4* Wv = reinterpret_cast<const float4*>(Wlds);

    const int* sp = edge_index + 3 * g0;      // 6 consecutive src indices
    const int* dp = edge_index + E + 3 * g0;  // 6 consecutive dst indices

    // --- all index loads first ---
    int s0 = sp[0], s1 = sp[1], s2 = sp[2];
    int d0 = dp[0], d1 = dp[1], d2 = dp[2];
    int s3 = 0, s4 = 0, s5 = 0, d3 = 0, d4 = 0, d5 = 0;
    if (has1) { s3 = sp[3]; s4 = sp[4]; s5 = sp[5];
                d3 = dp[3]; d4 = dp[4]; d5 = dp[5]; }

    // --- all 12 gathers in flight ---
    float4 a0 = Xv[s0 * 8 + l];
    float4 a1 = Xv[s1 * 8 + l];
    float4 a2 = Xv[s2 * 8 + l];
    float4 b0 = Xv[d0 * 8 + l];
    float4 b1 = Xv[d1 * 8 + l];
    float4 b2 = Xv[d2 * 8 + l];
    float4 a3 = Xv[s3 * 8 + l];
    float4 a4 = Xv[s4 * 8 + l];
    float4 a5 = Xv[s5 * 8 + l];
    float4 b3 = Xv[d3 * 8 + l];
    float4 b4 = Xv[d4 * 8 + l];
    float4 b5 = Xv[d5 * 8 + l];

    float4 xs0, xd0, xs1, xd1;
    xs0.x = a0.x + a1.x + a2.x; xs0.y = a0.y + a1.y + a2.y;
    xs0.z = a0.z + a1.z + a2.z; xs0.w = a0.w + a1.w + a2.w;
    xd0.x = b0.x + b1.x + b2.x; xd0.y = b0.y + b1.y + b2.y;
    xd0.z = b0.z + b1.z + b2.z; xd0.w = b0.w + b1.w + b2.w;
    xs1.x = a3.x + a4.x + a5.x; xs1.y = a3.y + a4.y + a5.y;
    xs1.z = a3.z + a4.z + a5.z; xs1.w = a3.w + a4.w + a5.w;
    xd1.x = b3.x + b4.x + b5.x; xd1.y = b3.y + b4.y + b5.y;
    xd1.z = b3.z + b4.z + b5.z; xd1.w = b3.w + b4.w + b5.w;

    float my0 = 0.f, ex0 = 0.f, my1 = 0.f, ex1 = 0.f;
    #pragma unroll
    for (int j = 0; j < NOUT; ++j) {
        float4 ws = Wv[j * 16 + l];
        float4 wd = Wv[j * 16 + 8 + l];
        float t0 = dot4(xs0, ws) + dot4(xd0, wd);
        float t1 = dot4(xs1, ws) + dot4(xd1, wd);
        t0 += __shfl_xor(t0, 1);  t1 += __shfl_xor(t1, 1);
        t0 += __shfl_xor(t0, 2);  t1 += __shfl_xor(t1, 2);
        t0 += __shfl_xor(t0, 4);  t1 += __shfl_xor(t1, 4);
        if (j < 8) {
            if (l == j) { my0 = t0; my1 = t1; }
        } else {
            ex0 = t0; ex1 = t1;
        }
    }

    out[g0 * 9 + l] = fast_tanh(my0);
    if (l == 0) out[g0 * 9 + 8] = fast_tanh(ex0);
    if (has1) {
        out[g1 * 9 + l] = fast_tanh(my1);
        if (l == 0) out[g1 * 9 + 8] = fast_tanh(ex1);
    }
}

extern "C" void kernel_launch(void* const* d_in, const int* in_sizes, int n_in,
                              void* d_out, int out_size, void* d_ws, size_t ws_size,
                              hipStream_t stream) {
    const float* x   = (const float*)d_in[0];
    const int*   ei  = (const int*)d_in[1];
    const float* W   = (const float*)d_in[2];
    float*       out = (float*)d_out;

    const int E = in_sizes[1] / 2;   // 3,000,000
    const int G = E / 3;             // 1,000,000

    const int subwaves = (G + 1) / 2;            // 2 groups per subwave
    const int blocks   = (subwaves + 31) / 32;   // 32 subwaves per 256-thr block
    hipLaunchKernelGGL(sheaf_kernel, dim3(blocks), dim3(256), 0, stream,
                       x, ei, W, out, G, E);
}